// Round 14
// baseline (224.693 us; speedup 1.0000x reference)
//
#include <hip/hip_runtime.h>
#include <math.h>

#define T_STEPS 256
#define BS      512
#define N       2048
#define WAVE    64
#define EPT     (N / WAVE)    // 32 elements per thread
#define FUDGE   1e-4f

typedef float vfloat4 __attribute__((ext_vector_type(4)));

// Non-rematerializable 16B load (INLINEASM defs can't be re-executed).
__device__ __forceinline__ vfloat4 load_pin_f4(const void* p) {
    vfloat4 r;
    asm volatile("global_load_dwordx4 %0, %1, off" : "=v"(r) : "v"(p) : "memory");
    return r;
}

#define PIN8(A, B) asm volatile("" \
    : "+v"((A)[(B)+0]), "+v"((A)[(B)+1]), "+v"((A)[(B)+2]), "+v"((A)[(B)+3]), \
      "+v"((A)[(B)+4]), "+v"((A)[(B)+5]), "+v"((A)[(B)+6]), "+v"((A)[(B)+7]))
#define PIN32(A) do { PIN8(A,0); PIN8(A,8); PIN8(A,16); PIN8(A,24); } while (0)

// --- wave64 all-lanes sum via DPP ----------------------------------------
template <int CTRL>
__device__ __forceinline__ float dpp_add(float v) {
    int sh = __builtin_amdgcn_update_dpp(0, __float_as_int(v), CTRL, 0xf, 0xf, true);
    return v + __int_as_float(sh);
}

__device__ __forceinline__ float wave_allsum(float v) {
    v = dpp_add<0x111>(v);  // row_shr:1
    v = dpp_add<0x112>(v);  // row_shr:2
    v = dpp_add<0x114>(v);  // row_shr:4
    v = dpp_add<0x118>(v);  // row_shr:8
    v = dpp_add<0x142>(v);  // row_bcast:15
    v = dpp_add<0x143>(v);  // row_bcast:31
    return __int_as_float(__builtin_amdgcn_readlane(__float_as_int(v), 63));
}

// R14 = the union of every verified fix, minimal exposed latency:
//  - single wave per batch element: NO barrier, NO cross-wave exchange
//  - coefficients register-resident via asm loads (non-remat) +
//    amdgpu_waves_per_eu(1,1) (R12-proven pin recipe; budget 512 regs)
//  - loop VMEM: one lane-0 store (no barrier -> no drain point)
//  - loop LDS: 3 broadcast ds_read_b32, prefetched one step ahead
// w_out scaled: w_t = sp_t*v_t, sp_t = wd^t => update one fma;
// norms = sqrt(FUDGE + (e*lr)^2 * sum h^2) (algebraically = reference).
__global__ __attribute__((amdgpu_waves_per_eu(1, 1))) __launch_bounds__(WAVE)
void legacy_elbo_scan_kernel(
    const float* __restrict__ noises,   // [T, BS]
    const float* __restrict__ ys,       // [T]
    const float* __restrict__ qs,       // [T]
    const float* __restrict__ z_biases, // [N]
    const float* __restrict__ w_in,     // [N]
    const float* __restrict__ w_inq,    // [N]
    const float* __restrict__ p_llr,
    const float* __restrict__ p_llrd,
    const float* __restrict__ p_sigb,
    const float* __restrict__ p_oscale,
    const float* __restrict__ p_ufs,
    const float* __restrict__ p_lwd,
    const float* __restrict__ p_qscale,
    const float* __restrict__ p_tauq,
    const float* __restrict__ p_tauy,
    float* __restrict__ out)            // [T, BS]
{
    const int lane = threadIdx.x;       // 0..63
    const int blk  = blockIdx.x;        // batch index k

    __shared__ float ys_s[T_STEPS];
    __shared__ float qs_s[T_STEPS];
    __shared__ float nz_s[T_STEPS];

    // Pinned coefficient loads: 12 x dwordx4 = 96 VGPRs, coalesced.
    const float4* zb4 = (const float4*)z_biases;
    const float4* wi4 = (const float4*)w_in;
    const float4* wq4 = (const float4*)w_inq;
    vfloat4 b[4], w[4], g[4];
#pragma unroll
    for (int c = 0; c < 4; ++c) {
        b[c] = load_pin_f4(zb4 + lane + (c << 6));
        w[c] = load_pin_f4(wi4 + lane + (c << 6));
        g[c] = load_pin_f4(wq4 + lane + (c << 6));
    }

    // Stage per-step scalars (4 rounds of 64).
#pragma unroll
    for (int i = 0; i < T_STEPS / WAVE; ++i) {
        const int t = lane + (i << 6);
        ys_s[t] = ys[t];
        qs_s[t] = qs[t];
        nz_s[t] = noises[t * BS + blk];
    }

    const float sigb    = p_sigb[0];
    const float llr     = p_llr[0];
    const float llrd    = p_llrd[0];
    const float oscale  = p_oscale[0];
    const float ufs     = p_ufs[0];
    const float lwd     = p_lwd[0];
    const float qscale  = p_qscale[0];
    const float tauq_m1 = p_tauq[0];
    const float tauy_m1 = p_tauy[0];

    const float lr0      = expf(llr);
    const float lr_decay = expf(llrd);
    const float wd       = expf(lwd);
    const float rwd      = 1.0f / wd;
    const float tauq     = 1.0f + log1pf(expf(tauq_m1));
    const float tauy     = 1.0f + log1pf(expf(tauy_m1));
    const float omtq     = 1.0f - tauq;
    const float omty     = 1.0f - tauy;

    // Drain asm loads, DATA-TIED (R10 lesson).
    asm volatile("s_waitcnt vmcnt(0)"
        : "+v"(b[0]), "+v"(b[1]), "+v"(b[2]), "+v"(b[3]),
          "+v"(w[0]), "+v"(w[1]), "+v"(w[2]), "+v"(w[3]),
          "+v"(g[0]), "+v"(g[1]), "+v"(g[2]), "+v"(g[3])
        :
        : "memory");

    // Unpack to scalar arrays; pre-scale bias; pin all 96.
    float bs_[EPT], cw[EPT], cg[EPT];
#pragma unroll
    for (int c = 0; c < 4; ++c) {
        bs_[4*c+0] = sigb * b[c].x; bs_[4*c+1] = sigb * b[c].y;
        bs_[4*c+2] = sigb * b[c].z; bs_[4*c+3] = sigb * b[c].w;
        cw[4*c+0] = w[c].x; cw[4*c+1] = w[c].y;
        cw[4*c+2] = w[c].z; cw[4*c+3] = w[c].w;
        cg[4*c+0] = g[c].x; cg[4*c+1] = g[c].y;
        cg[4*c+2] = g[c].z; cg[4*c+3] = g[c].w;
    }
    // NOTE: EPT=32 but loads covered indices lane + c*64 for c<4 => 16 elems?
    // No: 12 dwordx4 loads cover 4 chunks of each array (4*4=16 floats each).
    // We need 32 per array => 8 chunks. Extend with a second batch of loads.
    vfloat4 b2[4], w2[4], g2[4];
#pragma unroll
    for (int c = 0; c < 4; ++c) {
        b2[c] = load_pin_f4(zb4 + lane + ((c + 4) << 6));
        w2[c] = load_pin_f4(wi4 + lane + ((c + 4) << 6));
        g2[c] = load_pin_f4(wq4 + lane + ((c + 4) << 6));
    }
    asm volatile("s_waitcnt vmcnt(0)"
        : "+v"(b2[0]), "+v"(b2[1]), "+v"(b2[2]), "+v"(b2[3]),
          "+v"(w2[0]), "+v"(w2[1]), "+v"(w2[2]), "+v"(w2[3]),
          "+v"(g2[0]), "+v"(g2[1]), "+v"(g2[2]), "+v"(g2[3])
        :
        : "memory");
#pragma unroll
    for (int c = 0; c < 4; ++c) {
        bs_[16+4*c+0] = sigb * b2[c].x; bs_[16+4*c+1] = sigb * b2[c].y;
        bs_[16+4*c+2] = sigb * b2[c].z; bs_[16+4*c+3] = sigb * b2[c].w;
        cw[16+4*c+0] = w2[c].x; cw[16+4*c+1] = w2[c].y;
        cw[16+4*c+2] = w2[c].z; cw[16+4*c+3] = w2[c].w;
        cg[16+4*c+0] = g2[c].x; cg[16+4*c+1] = g2[c].y;
        cg[16+4*c+2] = g2[c].z; cg[16+4*c+3] = g2[c].w;
    }
    PIN32(bs_); PIN32(cw); PIN32(cg);

    // Persistent per-thread state.
    float v[EPT];
#pragma unroll
    for (int i = 0; i < EPT; ++i) v[i] = 0.0f;

    float u = 0.0f, e = 0.0f, lr_mult = 1.0f, ylp = 0.0f;
    float sp = 1.0f, rsp = 1.0f;        // wd^t and 1/wd^t

    __syncthreads();                    // drain staging (single wave)

    // Prologue: qlp/hb for step 0.
    float qlp = tauq * qs_s[0];
    float qsc = qscale * qlp;
    float hb[EPT];
#pragma unroll
    for (int i = 0; i < EPT; ++i) hb[i] = fmaf(qsc, cg[i], bs_[i]);

    float y_c = ys_s[0], n_c = nz_s[0];

    for (int t = 0; t < T_STEPS; ++t) {
        const int tn = (t + 1 < T_STEPS) ? t + 1 : t;
        const float q_n = qs_s[tn], y_n = ys_s[tn], n_n = nz_s[tn];

        const float x = fmaf(u, ufs, e) + n_c;

        float su0 = 0.f, su1 = 0.f, su2 = 0.f, su3 = 0.f;
        float sh0 = 0.f, sh1 = 0.f, sh2_ = 0.f, sh3 = 0.f;
        float h[EPT];
#pragma unroll
        for (int i = 0; i < EPT; ++i) {
            const float hv = fmaxf(fmaf(x, cw[i], hb[i]), 0.0f);
            h[i] = hv;
            switch (i & 3) {
              case 0: su0 = fmaf(v[i], hv, su0); sh0  = fmaf(hv, hv, sh0);  break;
              case 1: su1 = fmaf(v[i], hv, su1); sh1  = fmaf(hv, hv, sh1);  break;
              case 2: su2 = fmaf(v[i], hv, su2); sh2_ = fmaf(hv, hv, sh2_); break;
              default:su3 = fmaf(v[i], hv, su3); sh3  = fmaf(hv, hv, sh3);  break;
            }
        }
        const float su_t = wave_allsum((su0 + su1) + (su2 + su3));
        const float sh2  = wave_allsum((sh0 + sh1) + (sh2_ + sh3));

        u = sp * su_t;                  // w_t = sp * v_t
        if (lane == 0) out[t * BS + blk] = oscale * u;  // no barrier -> free

        ylp = omty * ylp + tauy * y_c;
        e = ylp - u;
        const float el = e * (lr0 * lr_mult);
        const float c  = el * rsp;      // dw coefficient in v-space

        // Next step's hb (independent of the reduction результат).
        qlp = omtq * qlp + tauq * q_n;
        qsc = qscale * qlp;
#pragma unroll
        for (int i = 0; i < EPT; ++i) {
            v[i] = fmaf(c, h[i], v[i]);
            hb[i] = fmaf(qsc, cg[i], bs_[i]);
        }

        const float nrm = sqrtf(fmaf(el * el, sh2, FUDGE));
        lr_mult *= __expf(-lr_decay * nrm);
        sp  *= wd;
        rsp *= rwd;

        y_c = y_n; n_c = n_n;
    }
}

extern "C" void kernel_launch(void* const* d_in, const int* in_sizes, int n_in,
                              void* d_out, int out_size, void* d_ws, size_t ws_size,
                              hipStream_t stream) {
    (void)in_sizes; (void)n_in; (void)d_ws; (void)ws_size; (void)out_size;
    const float* noises   = (const float*)d_in[0];
    const float* ys       = (const float*)d_in[1];
    const float* qs       = (const float*)d_in[2];
    const float* z_biases = (const float*)d_in[3];
    const float* w_in     = (const float*)d_in[4];
    const float* w_inq    = (const float*)d_in[5];
    const float* llr      = (const float*)d_in[6];
    const float* llrd     = (const float*)d_in[7];
    const float* sigb     = (const float*)d_in[8];
    const float* oscale   = (const float*)d_in[9];
    const float* ufs      = (const float*)d_in[10];
    const float* lwd      = (const float*)d_in[11];
    const float* qscale   = (const float*)d_in[12];
    const float* tauq     = (const float*)d_in[13];
    const float* tauy     = (const float*)d_in[14];
    float* out = (float*)d_out;

    hipLaunchKernelGGL(legacy_elbo_scan_kernel, dim3(BS), dim3(WAVE), 0, stream,
                       noises, ys, qs, z_biases, w_in, w_inq,
                       llr, llrd, sigb, oscale, ufs, lwd, qscale, tauq, tauy,
                       out);
}